// Round 11
// baseline (906.087 us; speedup 1.0000x reference)
//
#include <hip/hip_runtime.h>
#include <stdint.h>

#define NN 4096
#define DF 128
#define NBINS 16384          // fine bins; fits LDS (64 KiB u32)
#define NSLAB 256            // histogram slabs per graph
#define BORUVKA_ROUNDS 12

typedef __attribute__((ext_vector_type(8))) short short8;
typedef __attribute__((ext_vector_type(4))) float floatx4;
typedef __attribute__((ext_vector_type(4))) unsigned short ushort4_t;
typedef __attribute__((ext_vector_type(4))) int int4_t;

// ---------- helpers ----------
__device__ __forceinline__ unsigned bin_of(float v, float scale) {
  if (v < 0.f) v = 0.f;
  unsigned b = (unsigned)(v * scale);
  return b >= (unsigned)NBINS ? (unsigned)(NBINS - 1) : b;
}

// ---------- row squared norms for both graphs (fp32, matches reference) ----------
__global__ void k_rownorm(const float* __restrict__ x1, const float* __restrict__ x2,
                          float* __restrict__ sq) {
  int i = blockIdx.x * blockDim.x + threadIdx.x;
  if (i >= 2 * NN) return;
  const float* x = (i < NN) ? x1 : x2;
  int r = i & (NN - 1);
  const float* row = x + (size_t)r * DF;
  float s = 0.f;
  for (int k = 0; k < DF; ++k) s += row[k] * row[k];
  sq[i] = s;
}

// ---------- distance upper bound -> u16 quantization scales ----------
// hdrf: [0..1]=caps(u32), [2]=qscale, [3]=qinv
__global__ __launch_bounds__(256) void k_bound(const float* __restrict__ sq,
                                               float* __restrict__ hdrf) {
  int t = threadIdx.x;
  float m = 0.f;
  for (int i = t; i < 2 * NN; i += 256) m = fmaxf(m, sq[i]);
  for (int off = 32; off > 0; off >>= 1) m = fmaxf(m, __shfl_down(m, off, 64));
  __shared__ float wm[4];
  if ((t & 63) == 0) wm[t >> 6] = m;
  __syncthreads();
  if (t == 0) {
    float mm = fmaxf(fmaxf(wm[0], wm[1]), fmaxf(wm[2], wm[3]));
    float dbound = 2.f * sqrtf(mm);       // d <= |xi|+|xj| <= 2*max|x|
    hdrf[2] = 65535.f / dbound;
    hdrf[3] = dbound / 65535.f;
  }
}

// ---------- split fp32 -> (hi, lo) bf16 for error-compensated MFMA ----------
__global__ void k_split(const float* __restrict__ x1, const float* __restrict__ x2,
                        unsigned short* __restrict__ xh, unsigned short* __restrict__ xl) {
  int i = blockIdx.x * blockDim.x + threadIdx.x;
  if (i >= 2 * NN * DF) return;
  const float* x = (i < NN * DF) ? x1 : x2;
  float v = x[i & (NN * DF - 1)];
  unsigned u = __float_as_uint(v);
  unsigned hu = u & 0xffff0000u;
  float hf = __uint_as_float(hu);
  float lf = v - hf;
  unsigned lu = __float_as_uint(lf) & 0xffff0000u;
  xh[i] = (unsigned short)(hu >> 16);
  xl[i] = (unsigned short)(lu >> 16);
}

// ---------- distances via split-bf16 MFMA Gram, LDS-free (R7/R10-proven) ----------
__global__ __launch_bounds__(256) void k_dist(const unsigned short* __restrict__ Xhi,
                                              const unsigned short* __restrict__ Xlo,
                                              const float* __restrict__ sq,
                                              const float* __restrict__ hdrf,
                                              unsigned short* __restrict__ Qbase,
                                              unsigned* __restrict__ caps) {
  int g = blockIdx.z;
  const unsigned short* xh = Xhi + (size_t)g * NN * DF;
  const unsigned short* xl = Xlo + (size_t)g * NN * DF;
  const float* sqg = sq + g * NN;
  unsigned short* Q = Qbase + (size_t)g * NN * NN;
  float qs = hdrf[2];
  int t = threadIdx.x;
  int w = t >> 6, lane = t & 63;
  int m = lane & 15, quad = lane >> 4;
  int i0 = blockIdx.y * 128 + (w >> 1) * 64;
  int j0 = blockIdx.x * 128 + (w & 1) * 64;
  floatx4 acc[4][4];
#pragma unroll
  for (int ti = 0; ti < 4; ++ti)
#pragma unroll
    for (int tj = 0; tj < 4; ++tj) acc[ti][tj] = (floatx4){0.f, 0.f, 0.f, 0.f};
#pragma unroll
  for (int kc = 0; kc < DF; kc += 32) {
    short8 ah[4], al[4], bh[4], bl[4];
#pragma unroll
    for (int ti = 0; ti < 4; ++ti) {
      size_t ra = (size_t)(i0 + ti * 16 + m) * DF + kc + quad * 8;
      size_t rb = (size_t)(j0 + ti * 16 + m) * DF + kc + quad * 8;
      ah[ti] = *(const short8*)&xh[ra];
      al[ti] = *(const short8*)&xl[ra];
      bh[ti] = *(const short8*)&xh[rb];
      bl[ti] = *(const short8*)&xl[rb];
    }
#pragma unroll
    for (int ti = 0; ti < 4; ++ti)
#pragma unroll
      for (int tj = 0; tj < 4; ++tj) {
        acc[ti][tj] = __builtin_amdgcn_mfma_f32_16x16x32_bf16(ah[ti], bh[tj], acc[ti][tj], 0, 0, 0);
        acc[ti][tj] = __builtin_amdgcn_mfma_f32_16x16x32_bf16(ah[ti], bl[tj], acc[ti][tj], 0, 0, 0);
        acc[ti][tj] = __builtin_amdgcn_mfma_f32_16x16x32_bf16(al[ti], bh[tj], acc[ti][tj], 0, 0, 0);
      }
  }
  // C/D layout: col = lane&15 (j), row = quad*4 + reg (i)
  float sqj[4];
#pragma unroll
  for (int tj = 0; tj < 4; ++tj) sqj[tj] = sqg[j0 + tj * 16 + m];
  float mx = 0.f;
#pragma unroll
  for (int ti = 0; ti < 4; ++ti) {
#pragma unroll
    for (int r = 0; r < 4; ++r) {
      int i = i0 + ti * 16 + quad * 4 + r;
      float sqi = sqg[i];
      unsigned short* qrow = Q + (size_t)i * NN;
#pragma unroll
      for (int tj = 0; tj < 4; ++tj) {
        float d2 = sqi + sqj[tj] - 2.f * acc[ti][tj][r];
        d2 = fmaxf(d2, 0.f);
        float d = (d2 > 1e-12f) ? sqrtf(d2) : 0.f;
        mx = fmaxf(mx, d);
        unsigned q = (unsigned)(d * qs + 0.5f);
        if (q > 65535u) q = 65535u;
        qrow[j0 + tj * 16 + m] = (unsigned short)q;
      }
    }
  }
  for (int off = 32; off > 0; off >>= 1) mx = fmaxf(mx, __shfl_down(mx, off, 64));
  __shared__ float wmax[4];
  if (lane == 0) wmax[w] = mx;
  __syncthreads();
  if (t == 0) {
    float mm = fmaxf(fmaxf(wmax[0], wmax[1]), fmaxf(wmax[2], wmax[3]));
    atomicMax(&caps[g], __float_as_uint(mm));
  }
}

// ---------- Boruvka init ----------
// meta ints: [0..1]=mstcnt [2..3]=ncomp [8..31]=top ticket[g*12+r]
//            [32..1567]=sub tickets[g*768 + r*64 + grp]
#define META_INTS 1568
__global__ void k_binit(int* __restrict__ comp, unsigned long long* __restrict__ compbest,
                        unsigned long long* __restrict__ bestkey, int* __restrict__ meta) {
  int i = blockIdx.x * blockDim.x + threadIdx.x;
  if (i >= 2 * NN) return;
  comp[i] = i & (NN - 1);
  compbest[i] = ~0ull;
  bestkey[i] = ~0ull;
  if (i < META_INTS) meta[i] = 0;
  if (i == 0) {
    meta[2] = NN;
    meta[3] = NN;
  }
}

// ---------- fused Boruvka round: minedge (one block/row) + ticket-tree hook ----------
// key = (w16 << 24) | (v << 12) | j : unique => hook graph has only 2-cycles.
// Ordering WITHOUT fences: returning atomics + forced materialization chain.
//   block t0: old=atomicMin(ret) -> use(old) -> sub=atomicAdd(ret) -> if sub==63
//   -> top=atomicAdd(ret); top==63 => all 4096 blocks' mins completed at the
//   memory endpoint (atomics are memory-side, R4-measured). Only the single
//   hook block issues one __threadfence (acquire) before plain compbest reads
//   (R7-validated visibility; no other block reads compbest in-dispatch).
__global__ __launch_bounds__(256) void k_round(const unsigned short* __restrict__ Qbase,
                                               int* __restrict__ comp_base,
                                               unsigned long long* __restrict__ compbest_base,
                                               unsigned long long* __restrict__ bestkey_base,
                                               const float* __restrict__ hdrf,
                                               float* __restrict__ mstw_base,
                                               int* __restrict__ meta,
                                               int roundIdx) {
  int b = blockIdx.x;
  int g = b >> 12, v = b & (NN - 1);
  int t = threadIdx.x;
  int* comp = comp_base + g * NN;
  unsigned long long* cbest = compbest_base + (size_t)g * NN;
  unsigned long long* bkp = bestkey_base + (size_t)g * NN;
  bool alive = (meta[2 + g] > 1);

  __shared__ unsigned long long wmin[4];
  __shared__ int amlast;
  unsigned long long minold = 0;   // t0 only: returned value of the atomicMin
  bool didmin = false;

  if (alive) {
    int cv = comp[v];
    unsigned long long bk = bkp[v];
    bool valid = false;
    if (bk != ~0ull) {
      int bj = (int)(bk & 0xfffull);
      valid = (comp[bj] != cv);    // block-uniform (v is per-block)
    }
    if (valid) {
      if (t == 0) {
        minold = atomicMin(&cbest[cv], bk);
        didmin = true;
      }
    } else {
      const unsigned short* row = Qbase + ((size_t)g * NN + (size_t)v) * NN;
      unsigned long long best = ~0ull;
      for (int jb = t * 4; jb < NN; jb += 1024) {
        ushort4_t rw = *(const ushort4_t*)&row[jb];
        int4_t cj = *(const int4_t*)&comp[jb];
        for (int u = 0; u < 4; ++u) {
          if (cj[u] != cv) {
            unsigned long long key = ((unsigned long long)rw[u] << 24) |
                                     ((unsigned long long)v << 12) | (unsigned)(jb + u);
            if (key < best) best = key;
          }
        }
      }
      for (int off = 32; off > 0; off >>= 1) {
        unsigned long long o = __shfl_down(best, off, 64);
        if (o < best) best = o;
      }
      if ((t & 63) == 0) wmin[t >> 6] = best;
      __syncthreads();
      if (t == 0) {
        unsigned long long bb = wmin[0];
        for (int w = 1; w < 4; ++w)
          if (wmin[w] < bb) bb = wmin[w];
        bkp[v] = bb;
        if (bb != ~0ull) {
          minold = atomicMin(&cbest[cv], bb);
          didmin = true;
        }
      }
    }
  }
  __syncthreads();

  // ---- two-level ticket (t0 only); data-dependency ordering, no fences ----
  if (t == 0) {
    if (didmin) asm volatile("" : : "v"(minold));  // force vmcnt wait: min completed
    int last = 0;
    int sub = atomicAdd(&meta[32 + g * 768 + roundIdx * 64 + (v >> 6)], 1);
    if (sub == 63) {
      asm volatile("" : : "v"(sub));               // ordered: group done before top add
      int top = atomicAdd(&meta[8 + g * 12 + roundIdx], 1);
      last = (top == 63);
    }
    amlast = last;
  }
  __syncthreads();
  if (!amlast) return;
  if (!alive) return;
  __threadfence();   // single block: acquire before plain compbest reads

  // ---- hook/contract (256 threads, LDS; R7/R9-proven logic) ----
  float* mstw = mstw_base + g * (NN - 1);
  float qinv = hdrf[3];
  __shared__ int par[NN];
  __shared__ unsigned char live[NN];
  __shared__ int warr[4];
  for (int c = t; c < NN; c += 256) {
    unsigned long long key = cbest[c];
    bool a = (key != ~0ull);
    live[c] = a ? 1 : 0;
    int p = c;
    if (a) {
      int j = (int)(key & 0xfffull);
      p = comp[j];
    }
    par[c] = p;
  }
  __syncthreads();
  // break 2-cycles: smaller label becomes root (each thread writes own slots)
  for (int c = t; c < NN; c += 256) {
    int p = par[c];
    if (p != c && par[p] == c && c < p) par[c] = c;
  }
  __syncthreads();
  // emit one MST weight per hooked component (dequantized)
  for (int c = t; c < NN; c += 256) {
    if (live[c] && par[c] != c) {
      float wgt = (float)((unsigned)(cbest[c] >> 24)) * qinv;
      int slot = atomicAdd(&meta[g], 1);
      mstw[slot] = wgt;
    }
  }
  __syncthreads();
  // pointer jumping until stable
  for (;;) {
    int np[NN / 256];
    bool ch = false;
    int k = 0;
    for (int c = t; c < NN; c += 256, ++k) {
      int p = par[c];
      int pp = par[p];
      np[k] = pp;
      if (pp != p) ch = true;
    }
    __syncthreads();
    k = 0;
    for (int c = t; c < NN; c += 256, ++k) par[c] = np[k];
    if (!__syncthreads_or(ch)) break;
  }
  // count roots
  int cnt = 0;
  for (int c = t; c < NN; c += 256)
    if (live[c] && par[c] == c) cnt++;
  for (int off = 32; off > 0; off >>= 1) cnt += __shfl_down(cnt, off, 64);
  if ((t & 63) == 0) warr[t >> 6] = cnt;
  __syncthreads();
  // relabel + reset (plain dirty stores; flushed at dispatch end for next round)
  for (int vv = t; vv < NN; vv += 256) comp[vv] = par[comp[vv]];
  for (int c = t; c < NN; c += 256) cbest[c] = ~0ull;
  if (t == 0) meta[2 + g] = warr[0] + warr[1] + warr[2] + warr[3];
}

// ---------- histogram: per-block LDS hist over upper triangle (u16 D), slab dump ----------
__global__ __launch_bounds__(256) void k_hist(const unsigned short* __restrict__ Qbase,
                                              const unsigned* __restrict__ caps,
                                              const float* __restrict__ hdrf,
                                              unsigned* __restrict__ Hs) {
  __shared__ unsigned h[NBINS];
  int t = threadIdx.x;
  for (int i = t; i < NBINS; i += 256) h[i] = 0;
  int b = blockIdx.x;
  int g = b >> 8, s = b & (NSLAB - 1);
  const unsigned short* Q = Qbase + (size_t)g * NN * NN;
  float cap = __uint_as_float(caps[g]);
  float capmax = fmaxf(__uint_as_float(caps[0]), __uint_as_float(caps[1]));
  float scale = (float)NBINS / capmax;
  float qinv = hdrf[3];
  __syncthreads();
  for (int p = s; p < NN / 2; p += NSLAB) {
    int r1 = p, r2 = NN - 1 - p;
    const unsigned short* row1 = Q + (size_t)r1 * NN;
    const unsigned short* row2 = Q + (size_t)r2 * NN;
    for (int j = r1 + 1 + t; j < NN; j += 256)
      atomicAdd(&h[bin_of(cap - (float)row1[j] * qinv, scale)], 1u);
    for (int j = r2 + 1 + t; j < NN; j += 256)
      atomicAdd(&h[bin_of(cap - (float)row2[j] * qinv, scale)], 1u);
  }
  __syncthreads();
  unsigned* slab = Hs + (size_t)b * NBINS;
  for (int i = t; i < NBINS; i += 256) slab[i] = h[i];
}

// ---------- move tree edges to persistence 0 (slab 0; same dequant grid => exact) ----------
__global__ void k_treefix(const float* __restrict__ twbase, const unsigned* __restrict__ caps,
                          unsigned* __restrict__ Hs) {
  int g = blockIdx.y;
  unsigned* hist = Hs + (size_t)(g * NSLAB) * NBINS;
  float cap = __uint_as_float(caps[g]);
  float capmax = fmaxf(__uint_as_float(caps[0]), __uint_as_float(caps[1]));
  float scale = (float)NBINS / capmax;
  int idx = blockIdx.x * blockDim.x + threadIdx.x;
  if (idx < NN - 1) {
    float w = twbase[g * (NN - 1) + idx];
    atomicSub(&hist[bin_of(cap - w, scale)], 1u);  // may wrap; per-bin total stays >= 0
    atomicAdd(&hist[0], 1u);
  }
}

// ---------- merge 256 slabs per graph -> Hm[2][NBINS] ----------
__global__ __launch_bounds__(256) void k_merge(const unsigned* __restrict__ Hs,
                                               unsigned* __restrict__ Hm) {
  int id = blockIdx.x * 256 + threadIdx.x;  // 0 .. 2*NBINS-1
  int g = id >> 14;
  int i = id & (NBINS - 1);
  const unsigned* base = Hs + (size_t)(g * NSLAB) * NBINS + i;
  unsigned sum = 0;
  for (int s = 0; s < NSLAB; ++s) sum += base[(size_t)s * NBINS];
  Hm[id] = sum;
}

// ---------- W1: single block computes sum |running prefix| * dt ----------
__global__ __launch_bounds__(256) void k_w1(const unsigned* __restrict__ Hm,
                                            const unsigned* __restrict__ caps,
                                            float* __restrict__ out) {
  int t = threadIdx.x;
  const int PB = NBINS / 256;  // 64 bins per thread
  int base = t * PB;
  long long tsum = 0;
  for (int i = 0; i < PB; ++i)
    tsum += (long long)(int)(Hm[base + i] - Hm[NBINS + base + i]);
  int lane = t & 63, wid = t >> 6;
  long long incl = tsum;
  for (int off = 1; off < 64; off <<= 1) {
    long long o = __shfl_up(incl, off, 64);
    if (lane >= off) incl += o;
  }
  __shared__ long long wtot[4];
  if (lane == 63) wtot[wid] = incl;
  __syncthreads();
  long long run = incl - tsum;
  for (int w = 0; w < wid; ++w) run += wtot[w];
  unsigned long long local = 0;
  for (int i = 0; i < PB; ++i) {
    run += (long long)(int)(Hm[base + i] - Hm[NBINS + base + i]);
    local += (unsigned long long)(run < 0 ? -run : run);
  }
  for (int off = 32; off > 0; off >>= 1) local += __shfl_down(local, off, 64);
  __shared__ unsigned long long wl[4];
  if (lane == 0) wl[wid] = local;
  __syncthreads();
  if (t == 0) {
    float capmax = fmaxf(__uint_as_float(caps[0]), __uint_as_float(caps[1]));
    double dt = (double)capmax / (double)NBINS;
    out[0] = (float)((double)(wl[0] + wl[1] + wl[2] + wl[3]) * dt);
  }
}

__global__ void k_fail(float* out) { out[0] = -1234567.0f; }

extern "C" void kernel_launch(void* const* d_in, const int* in_sizes, int n_in,
                              void* d_out, int out_size, void* d_ws, size_t ws_size,
                              hipStream_t stream) {
  const float* x1 = (const float*)d_in[0];
  const float* x2 = (const float*)d_in[2];
  float* out = (float*)d_out;
  char* ws = (char*)d_ws;

  const size_t offQ = 0;                                        // u16 D: 64 MiB
  const size_t offS = 2ull * NN * NN * 2ull;                    // slabs: 32 MiB
  const size_t offHm = offS + 2ull * NSLAB * NBINS * 4ull;      // 128 KiB merged hist
  const size_t offHdr = offHm + 2ull * NBINS * 4ull;            // caps+qscale+qinv
  const size_t offSq = offHdr + 64;
  const size_t offTw = offSq + 2ull * NN * 4ull;
  const size_t offCb = (offTw + 2ull * (NN - 1) * 4ull + 7ull) & ~7ull;
  const size_t offBk = offCb + 2ull * NN * 8ull;                // bestkey cache
  const size_t offCp = offBk + 2ull * NN * 8ull;
  const size_t offMeta = offCp + 2ull * NN * 4ull;              // META_INTS ints
  const size_t needed = offMeta + (size_t)META_INTS * 4ull;
  if (ws_size < needed) {
    hipLaunchKernelGGL(k_fail, dim3(1), dim3(1), 0, stream, out);
    return;
  }

  unsigned short* Qbase = (unsigned short*)(ws + offQ);
  unsigned* Hs = (unsigned*)(ws + offS);
  // Xhi/Xlo (4 MiB) transiently live in the slab region (dead before k_hist writes it)
  unsigned short* Xhi = (unsigned short*)(ws + offS);
  unsigned short* Xlo = (unsigned short*)(ws + offS + 2ull * NN * DF * 2ull);
  unsigned* Hm = (unsigned*)(ws + offHm);
  unsigned* caps = (unsigned*)(ws + offHdr);
  float* hdrf = (float*)(ws + offHdr);
  float* sq = (float*)(ws + offSq);
  float* tw = (float*)(ws + offTw);
  unsigned long long* compbest = (unsigned long long*)(ws + offCb);
  unsigned long long* bestkey = (unsigned long long*)(ws + offBk);
  int* comp = (int*)(ws + offCp);
  int* meta = (int*)(ws + offMeta);

  // zero header (caps; qscale/qinv overwritten by k_bound)
  hipMemsetAsync(ws + offHdr, 0, 64, stream);

  hipLaunchKernelGGL(k_rownorm, dim3((2 * NN + 255) / 256), dim3(256), 0, stream, x1, x2, sq);
  hipLaunchKernelGGL(k_bound, dim3(1), dim3(256), 0, stream, sq, hdrf);
  hipLaunchKernelGGL(k_split, dim3((2 * NN * DF + 255) / 256), dim3(256), 0, stream,
                     x1, x2, Xhi, Xlo);
  hipLaunchKernelGGL(k_dist, dim3(NN / 128, NN / 128, 2), dim3(256), 0, stream,
                     Xhi, Xlo, sq, hdrf, Qbase, caps);
  hipLaunchKernelGGL(k_binit, dim3((2 * NN + 255) / 256), dim3(256), 0, stream,
                     comp, compbest, bestkey, meta);
  for (int r = 0; r < BORUVKA_ROUNDS; ++r) {
    hipLaunchKernelGGL(k_round, dim3(2 * NN), dim3(256), 0, stream,
                       Qbase, comp, compbest, bestkey, hdrf, tw, meta, r);
  }
  hipLaunchKernelGGL(k_hist, dim3(2 * NSLAB), dim3(256), 0, stream, Qbase, caps, hdrf, Hs);
  hipLaunchKernelGGL(k_treefix, dim3(16, 2), dim3(256), 0, stream, tw, caps, Hs);
  hipLaunchKernelGGL(k_merge, dim3(2 * NBINS / 256), dim3(256), 0, stream, Hs, Hm);
  hipLaunchKernelGGL(k_w1, dim3(1), dim3(256), 0, stream, Hm, caps, out);
}

// Round 12
// 437.730 us; speedup vs baseline: 2.0700x; 2.0700x over previous
//
#include <hip/hip_runtime.h>
#include <stdint.h>

#define NN 4096
#define DF 128
#define NBINS 16384          // fine bins; fits LDS (64 KiB u32)
#define NSLAB 256            // histogram slabs per graph
#define BORUVKA_ROUNDS 12

typedef __attribute__((ext_vector_type(8))) short short8;
typedef __attribute__((ext_vector_type(4))) float floatx4;
typedef __attribute__((ext_vector_type(4))) unsigned short ushort4_t;
typedef __attribute__((ext_vector_type(4))) int int4_t;

// ---------- helpers ----------
__device__ __forceinline__ unsigned bin_of(float v, float scale) {
  if (v < 0.f) v = 0.f;
  unsigned b = (unsigned)(v * scale);
  return b >= (unsigned)NBINS ? (unsigned)(NBINS - 1) : b;
}

// ---------- row squared norms for both graphs (fp32, matches reference) ----------
__global__ void k_rownorm(const float* __restrict__ x1, const float* __restrict__ x2,
                          float* __restrict__ sq) {
  int i = blockIdx.x * blockDim.x + threadIdx.x;
  if (i >= 2 * NN) return;
  const float* x = (i < NN) ? x1 : x2;
  int r = i & (NN - 1);
  const float* row = x + (size_t)r * DF;
  float s = 0.f;
  for (int k = 0; k < DF; ++k) s += row[k] * row[k];
  sq[i] = s;
}

// ---------- distance upper bound -> u16 quantization scales ----------
// hdrf: [0..1]=caps(u32), [2]=qscale, [3]=qinv
__global__ __launch_bounds__(256) void k_bound(const float* __restrict__ sq,
                                               float* __restrict__ hdrf) {
  int t = threadIdx.x;
  float m = 0.f;
  for (int i = t; i < 2 * NN; i += 256) m = fmaxf(m, sq[i]);
  for (int off = 32; off > 0; off >>= 1) m = fmaxf(m, __shfl_down(m, off, 64));
  __shared__ float wm[4];
  if ((t & 63) == 0) wm[t >> 6] = m;
  __syncthreads();
  if (t == 0) {
    float mm = fmaxf(fmaxf(wm[0], wm[1]), fmaxf(wm[2], wm[3]));
    float dbound = 2.f * sqrtf(mm);       // d <= |xi|+|xj| <= 2*max|x|
    hdrf[2] = 65535.f / dbound;
    hdrf[3] = dbound / 65535.f;
  }
}

// ---------- split fp32 -> (hi, lo) bf16 for error-compensated MFMA ----------
__global__ void k_split(const float* __restrict__ x1, const float* __restrict__ x2,
                        unsigned short* __restrict__ xh, unsigned short* __restrict__ xl) {
  int i = blockIdx.x * blockDim.x + threadIdx.x;
  if (i >= 2 * NN * DF) return;
  const float* x = (i < NN * DF) ? x1 : x2;
  float v = x[i & (NN * DF - 1)];
  unsigned u = __float_as_uint(v);
  unsigned hu = u & 0xffff0000u;
  float hf = __uint_as_float(hu);
  float lf = v - hf;
  unsigned lu = __float_as_uint(lf) & 0xffff0000u;
  xh[i] = (unsigned short)(hu >> 16);
  xl[i] = (unsigned short)(lu >> 16);
}

// ---------- distances via split-bf16 MFMA Gram, LDS-free, SYMMETRIC ----------
// Only tiles bi<=bj are computed (D symmetric: MFMA dot(i,j)==dot(j,i), same
// k-order). C-layout gives each lane 4 consecutive-i values at fixed j ->
// the TRANSPOSED write Q[j][i..i+3] is one 8B ushort4 store (cheap path).
// Diagonal tiles: transpose write alone covers the whole block. Off-diagonal:
// add the scattered 2B normal write for Q[i][j].
__global__ __launch_bounds__(256) void k_dist(const unsigned short* __restrict__ Xhi,
                                              const unsigned short* __restrict__ Xlo,
                                              const float* __restrict__ sq,
                                              const float* __restrict__ hdrf,
                                              unsigned short* __restrict__ Qbase,
                                              unsigned* __restrict__ caps) {
  int bi = blockIdx.y, bj = blockIdx.x;
  if (bi > bj) return;                       // triangle only
  bool offdiag = (bi != bj);
  int g = blockIdx.z;
  const unsigned short* xh = Xhi + (size_t)g * NN * DF;
  const unsigned short* xl = Xlo + (size_t)g * NN * DF;
  const float* sqg = sq + g * NN;
  unsigned short* Q = Qbase + (size_t)g * NN * NN;
  float qs = hdrf[2];
  int t = threadIdx.x;
  int w = t >> 6, lane = t & 63;
  int m = lane & 15, quad = lane >> 4;
  int i0 = bi * 128 + (w >> 1) * 64;
  int j0 = bj * 128 + (w & 1) * 64;
  floatx4 acc[4][4];
#pragma unroll
  for (int ti = 0; ti < 4; ++ti)
#pragma unroll
    for (int tj = 0; tj < 4; ++tj) acc[ti][tj] = (floatx4){0.f, 0.f, 0.f, 0.f};
#pragma unroll
  for (int kc = 0; kc < DF; kc += 32) {
    short8 ah[4], al[4], bh[4], bl[4];
#pragma unroll
    for (int ti = 0; ti < 4; ++ti) {
      size_t ra = (size_t)(i0 + ti * 16 + m) * DF + kc + quad * 8;
      size_t rb = (size_t)(j0 + ti * 16 + m) * DF + kc + quad * 8;
      ah[ti] = *(const short8*)&xh[ra];
      al[ti] = *(const short8*)&xl[ra];
      bh[ti] = *(const short8*)&xh[rb];
      bl[ti] = *(const short8*)&xl[rb];
    }
#pragma unroll
    for (int ti = 0; ti < 4; ++ti)
#pragma unroll
      for (int tj = 0; tj < 4; ++tj) {
        acc[ti][tj] = __builtin_amdgcn_mfma_f32_16x16x32_bf16(ah[ti], bh[tj], acc[ti][tj], 0, 0, 0);
        acc[ti][tj] = __builtin_amdgcn_mfma_f32_16x16x32_bf16(ah[ti], bl[tj], acc[ti][tj], 0, 0, 0);
        acc[ti][tj] = __builtin_amdgcn_mfma_f32_16x16x32_bf16(al[ti], bh[tj], acc[ti][tj], 0, 0, 0);
      }
  }
  // C/D layout: col = lane&15 (j), row = quad*4 + reg (i)
  float sqj[4];
#pragma unroll
  for (int tj = 0; tj < 4; ++tj) sqj[tj] = sqg[j0 + tj * 16 + m];
  float mx = 0.f;
#pragma unroll
  for (int ti = 0; ti < 4; ++ti) {
    int ib = i0 + ti * 16 + quad * 4;
    float sqiv[4];
#pragma unroll
    for (int r = 0; r < 4; ++r) sqiv[r] = sqg[ib + r];
#pragma unroll
    for (int tj = 0; tj < 4; ++tj) {
      int jj = j0 + tj * 16 + m;
      ushort4_t qv;
#pragma unroll
      for (int r = 0; r < 4; ++r) {
        float d2 = sqiv[r] + sqj[tj] - 2.f * acc[ti][tj][r];
        d2 = fmaxf(d2, 0.f);
        float d = (d2 > 1e-12f) ? sqrtf(d2) : 0.f;
        mx = fmaxf(mx, d);
        unsigned q = (unsigned)(d * qs + 0.5f);
        if (q > 65535u) q = 65535u;
        qv[r] = (unsigned short)q;
      }
      // transposed half: one 8B store (4 consecutive i in row jj)
      *(ushort4_t*)&Q[(size_t)jj * NN + ib] = qv;
      // normal half (off-diagonal tiles only): scattered 2B stores
      if (offdiag) {
#pragma unroll
        for (int r = 0; r < 4; ++r) Q[(size_t)(ib + r) * NN + jj] = qv[r];
      }
    }
  }
  for (int off = 32; off > 0; off >>= 1) mx = fmaxf(mx, __shfl_down(mx, off, 64));
  __shared__ float wmax[4];
  if (lane == 0) wmax[w] = mx;
  __syncthreads();
  if (t == 0) {
    float mm = fmaxf(fmaxf(wmax[0], wmax[1]), fmaxf(wmax[2], wmax[3]));
    atomicMax(&caps[g], __float_as_uint(mm));
  }
}

// ---------- Boruvka init ----------
__global__ void k_binit(int* __restrict__ comp, unsigned long long* __restrict__ compbest,
                        unsigned long long* __restrict__ bestkey,
                        int* __restrict__ mstcnt, int* __restrict__ ncomp) {
  int i = blockIdx.x * blockDim.x + threadIdx.x;
  if (i >= 2 * NN) return;
  comp[i] = i & (NN - 1);
  compbest[i] = ~0ull;
  bestkey[i] = ~0ull;
  if ((i & (NN - 1)) == 0) {
    mstcnt[i >> 12] = 0;
    ncomp[i >> 12] = NN;
  }
}

// ---------- Boruvka step 1 (R6/R10-proven, fence-free): per-row min edge ----------
// key = (w16 << 24) | (v << 12) | j : unique => hook graph has only 2-cycles.
// Cached candidate valid while its target stays outside comp[v].
__global__ __launch_bounds__(256) void k_minedge(const unsigned short* __restrict__ Qbase,
                                                 const int* __restrict__ comp_base,
                                                 unsigned long long* __restrict__ compbest_base,
                                                 unsigned long long* __restrict__ bestkey_base,
                                                 const int* __restrict__ ncomp) {
  int g = blockIdx.y;
  if (ncomp[g] == 1) return;
  int v = blockIdx.x;
  const int* comp = comp_base + g * NN;
  unsigned long long* cbest = compbest_base + (size_t)g * NN;
  unsigned long long* bkp = bestkey_base + (size_t)g * NN;
  int cv = comp[v];
  int t = threadIdx.x;
  unsigned long long bk = bkp[v];
  if (bk != ~0ull) {
    int bj = (int)(bk & 0xfffull);
    if (comp[bj] != cv) {           // cache still valid: skip the row scan
      if (t == 0) atomicMin(&cbest[cv], bk);
      return;
    }
  }
  const unsigned short* row = Qbase + ((size_t)g * NN + (size_t)v) * NN;
  unsigned long long best = ~0ull;
  for (int jb = t * 4; jb < NN; jb += 1024) {
    ushort4_t rw = *(const ushort4_t*)&row[jb];
    int4_t cj = *(const int4_t*)&comp[jb];
    for (int u = 0; u < 4; ++u) {
      if (cj[u] != cv) {
        unsigned long long key = ((unsigned long long)rw[u] << 24) |
                                 ((unsigned long long)v << 12) | (unsigned)(jb + u);
        if (key < best) best = key;
      }
    }
  }
  for (int off = 32; off > 0; off >>= 1) {
    unsigned long long o = __shfl_down(best, off, 64);
    if (o < best) best = o;
  }
  __shared__ unsigned long long wmin[4];
  if ((t & 63) == 0) wmin[t >> 6] = best;
  __syncthreads();
  if (t == 0) {
    unsigned long long bb = wmin[0];
    for (int w = 1; w < 4; ++w)
      if (wmin[w] < bb) bb = wmin[w];
    bkp[v] = bb;
    if (bb != ~0ull) atomicMin(&cbest[cv], bb);
  }
}

// ---------- Boruvka step 2 (R6/R10-proven): hook/contract ----------
__global__ __launch_bounds__(1024) void k_hook(unsigned long long* __restrict__ compbest_base,
                                               int* __restrict__ comp_base,
                                               const float* __restrict__ hdrf,
                                               float* __restrict__ mstw_base,
                                               int* __restrict__ mstcnt,
                                               int* __restrict__ ncomp) {
  int g = blockIdx.x;
  if (ncomp[g] == 1) return;
  unsigned long long* cb = compbest_base + (size_t)g * NN;
  int* comp = comp_base + g * NN;
  float* mstw = mstw_base + g * (NN - 1);
  float qinv = hdrf[3];
  __shared__ int par[NN];
  __shared__ unsigned char live[NN];
  __shared__ int newcnt;
  int t = threadIdx.x;
  if (t == 0) newcnt = 0;
  for (int c = t; c < NN; c += 1024) {
    unsigned long long key = cb[c];
    bool a = (key != ~0ull);
    live[c] = a ? 1 : 0;
    int p = c;
    if (a) {
      int j = (int)(key & 0xfffull);
      p = comp[j];
    }
    par[c] = p;
  }
  __syncthreads();
  for (int c = t; c < NN; c += 1024) {
    int p = par[c];
    if (p != c && par[p] == c && c < p) par[c] = c;
  }
  __syncthreads();
  for (int c = t; c < NN; c += 1024) {
    if (live[c] && par[c] != c) {
      float w = (float)((unsigned)(cb[c] >> 24)) * qinv;  // dequantized MST weight
      int slot = atomicAdd(&mstcnt[g], 1);
      mstw[slot] = w;
    }
  }
  __syncthreads();
  for (int it = 0; it < 12; ++it) {
    int np[NN / 1024];
    for (int c = t, k = 0; c < NN; c += 1024, ++k) np[k] = par[par[c]];
    __syncthreads();
    for (int c = t, k = 0; c < NN; c += 1024, ++k) par[c] = np[k];
    __syncthreads();
  }
  int cnt = 0;
  for (int c = t; c < NN; c += 1024)
    if (live[c] && par[c] == c) cnt++;
  for (int off = 32; off > 0; off >>= 1) cnt += __shfl_down(cnt, off, 64);
  if ((t & 63) == 0 && cnt) atomicAdd(&newcnt, cnt);
  for (int v = t; v < NN; v += 1024) comp[v] = par[comp[v]];
  for (int c = t; c < NN; c += 1024) cb[c] = ~0ull;
  __syncthreads();
  if (t == 0) ncomp[g] = newcnt;
}

// ---------- histogram: per-block LDS hist over upper triangle (u16 D), slab dump ----------
__global__ __launch_bounds__(256) void k_hist(const unsigned short* __restrict__ Qbase,
                                              const unsigned* __restrict__ caps,
                                              const float* __restrict__ hdrf,
                                              unsigned* __restrict__ Hs) {
  __shared__ unsigned h[NBINS];
  int t = threadIdx.x;
  for (int i = t; i < NBINS; i += 256) h[i] = 0;
  int b = blockIdx.x;
  int g = b >> 8, s = b & (NSLAB - 1);
  const unsigned short* Q = Qbase + (size_t)g * NN * NN;
  float cap = __uint_as_float(caps[g]);
  float capmax = fmaxf(__uint_as_float(caps[0]), __uint_as_float(caps[1]));
  float scale = (float)NBINS / capmax;
  float qinv = hdrf[3];
  __syncthreads();
  for (int p = s; p < NN / 2; p += NSLAB) {
    int r1 = p, r2 = NN - 1 - p;
    const unsigned short* row1 = Q + (size_t)r1 * NN;
    const unsigned short* row2 = Q + (size_t)r2 * NN;
    for (int j = r1 + 1 + t; j < NN; j += 256)
      atomicAdd(&h[bin_of(cap - (float)row1[j] * qinv, scale)], 1u);
    for (int j = r2 + 1 + t; j < NN; j += 256)
      atomicAdd(&h[bin_of(cap - (float)row2[j] * qinv, scale)], 1u);
  }
  __syncthreads();
  unsigned* slab = Hs + (size_t)b * NBINS;
  for (int i = t; i < NBINS; i += 256) slab[i] = h[i];
}

// ---------- move tree edges to persistence 0 (slab 0; same dequant grid => exact) ----------
__global__ void k_treefix(const float* __restrict__ twbase, const unsigned* __restrict__ caps,
                          unsigned* __restrict__ Hs) {
  int g = blockIdx.y;
  unsigned* hist = Hs + (size_t)(g * NSLAB) * NBINS;
  float cap = __uint_as_float(caps[g]);
  float capmax = fmaxf(__uint_as_float(caps[0]), __uint_as_float(caps[1]));
  float scale = (float)NBINS / capmax;
  int idx = blockIdx.x * blockDim.x + threadIdx.x;
  if (idx < NN - 1) {
    float w = twbase[g * (NN - 1) + idx];
    atomicSub(&hist[bin_of(cap - w, scale)], 1u);  // may wrap; per-bin total stays >= 0
    atomicAdd(&hist[0], 1u);
  }
}

// ---------- merge 256 slabs per graph -> Hm[2][NBINS] ----------
__global__ __launch_bounds__(256) void k_merge(const unsigned* __restrict__ Hs,
                                               unsigned* __restrict__ Hm) {
  int id = blockIdx.x * 256 + threadIdx.x;  // 0 .. 2*NBINS-1
  int g = id >> 14;
  int i = id & (NBINS - 1);
  const unsigned* base = Hs + (size_t)(g * NSLAB) * NBINS + i;
  unsigned sum = 0;
  for (int s = 0; s < NSLAB; ++s) sum += base[(size_t)s * NBINS];
  Hm[id] = sum;
}

// ---------- W1: single block computes sum |running prefix| * dt ----------
__global__ __launch_bounds__(256) void k_w1(const unsigned* __restrict__ Hm,
                                            const unsigned* __restrict__ caps,
                                            float* __restrict__ out) {
  int t = threadIdx.x;
  const int PB = NBINS / 256;  // 64 bins per thread
  int base = t * PB;
  long long tsum = 0;
  for (int i = 0; i < PB; ++i)
    tsum += (long long)(int)(Hm[base + i] - Hm[NBINS + base + i]);
  int lane = t & 63, wid = t >> 6;
  long long incl = tsum;
  for (int off = 1; off < 64; off <<= 1) {
    long long o = __shfl_up(incl, off, 64);
    if (lane >= off) incl += o;
  }
  __shared__ long long wtot[4];
  if (lane == 63) wtot[wid] = incl;
  __syncthreads();
  long long run = incl - tsum;
  for (int w = 0; w < wid; ++w) run += wtot[w];
  unsigned long long local = 0;
  for (int i = 0; i < PB; ++i) {
    run += (long long)(int)(Hm[base + i] - Hm[NBINS + base + i]);
    local += (unsigned long long)(run < 0 ? -run : run);
  }
  for (int off = 32; off > 0; off >>= 1) local += __shfl_down(local, off, 64);
  __shared__ unsigned long long wl[4];
  if (lane == 0) wl[wid] = local;
  __syncthreads();
  if (t == 0) {
    float capmax = fmaxf(__uint_as_float(caps[0]), __uint_as_float(caps[1]));
    double dt = (double)capmax / (double)NBINS;
    out[0] = (float)((double)(wl[0] + wl[1] + wl[2] + wl[3]) * dt);
  }
}

__global__ void k_fail(float* out) { out[0] = -1234567.0f; }

extern "C" void kernel_launch(void* const* d_in, const int* in_sizes, int n_in,
                              void* d_out, int out_size, void* d_ws, size_t ws_size,
                              hipStream_t stream) {
  const float* x1 = (const float*)d_in[0];
  const float* x2 = (const float*)d_in[2];
  float* out = (float*)d_out;
  char* ws = (char*)d_ws;

  const size_t offQ = 0;                                        // u16 D: 64 MiB
  const size_t offS = 2ull * NN * NN * 2ull;                    // slabs: 32 MiB
  const size_t offHm = offS + 2ull * NSLAB * NBINS * 4ull;      // 128 KiB merged hist
  const size_t offHdr = offHm + 2ull * NBINS * 4ull;            // caps+qscale+qinv
  const size_t offSq = offHdr + 64;
  const size_t offTw = offSq + 2ull * NN * 4ull;
  const size_t offCb = (offTw + 2ull * (NN - 1) * 4ull + 7ull) & ~7ull;
  const size_t offBk = offCb + 2ull * NN * 8ull;                // bestkey cache
  const size_t offCp = offBk + 2ull * NN * 8ull;
  const size_t offMeta = offCp + 2ull * NN * 4ull;              // mstcnt[2], ncomp[2]
  const size_t needed = offMeta + 64;
  if (ws_size < needed) {
    hipLaunchKernelGGL(k_fail, dim3(1), dim3(1), 0, stream, out);
    return;
  }

  unsigned short* Qbase = (unsigned short*)(ws + offQ);
  unsigned* Hs = (unsigned*)(ws + offS);
  // Xhi/Xlo (4 MiB) transiently live in the slab region (dead before k_hist writes it)
  unsigned short* Xhi = (unsigned short*)(ws + offS);
  unsigned short* Xlo = (unsigned short*)(ws + offS + 2ull * NN * DF * 2ull);
  unsigned* Hm = (unsigned*)(ws + offHm);
  unsigned* caps = (unsigned*)(ws + offHdr);
  float* hdrf = (float*)(ws + offHdr);
  float* sq = (float*)(ws + offSq);
  float* tw = (float*)(ws + offTw);
  unsigned long long* compbest = (unsigned long long*)(ws + offCb);
  unsigned long long* bestkey = (unsigned long long*)(ws + offBk);
  int* comp = (int*)(ws + offCp);
  int* mstcnt = (int*)(ws + offMeta);
  int* ncomp = (int*)(ws + offMeta + 8);

  // zero header (caps; qscale/qinv overwritten by k_bound)
  hipMemsetAsync(ws + offHdr, 0, 64, stream);

  hipLaunchKernelGGL(k_rownorm, dim3((2 * NN + 255) / 256), dim3(256), 0, stream, x1, x2, sq);
  hipLaunchKernelGGL(k_bound, dim3(1), dim3(256), 0, stream, sq, hdrf);
  hipLaunchKernelGGL(k_split, dim3((2 * NN * DF + 255) / 256), dim3(256), 0, stream,
                     x1, x2, Xhi, Xlo);
  hipLaunchKernelGGL(k_dist, dim3(NN / 128, NN / 128, 2), dim3(256), 0, stream,
                     Xhi, Xlo, sq, hdrf, Qbase, caps);
  hipLaunchKernelGGL(k_binit, dim3((2 * NN + 255) / 256), dim3(256), 0, stream,
                     comp, compbest, bestkey, mstcnt, ncomp);
  for (int r = 0; r < BORUVKA_ROUNDS; ++r) {
    hipLaunchKernelGGL(k_minedge, dim3(NN, 2), dim3(256), 0, stream,
                       Qbase, comp, compbest, bestkey, ncomp);
    hipLaunchKernelGGL(k_hook, dim3(2), dim3(1024), 0, stream,
                       compbest, comp, hdrf, tw, mstcnt, ncomp);
  }
  hipLaunchKernelGGL(k_hist, dim3(2 * NSLAB), dim3(256), 0, stream, Qbase, caps, hdrf, Hs);
  hipLaunchKernelGGL(k_treefix, dim3(16, 2), dim3(256), 0, stream, tw, caps, Hs);
  hipLaunchKernelGGL(k_merge, dim3(2 * NBINS / 256), dim3(256), 0, stream, Hs, Hm);
  hipLaunchKernelGGL(k_w1, dim3(1), dim3(256), 0, stream, Hm, caps, out);
}

// Round 13
// 412.822 us; speedup vs baseline: 2.1949x; 1.0603x over previous
//
#include <hip/hip_runtime.h>
#include <stdint.h>

#define NN 4096
#define DF 128
#define NBINS 16384          // fine bins; fits LDS (64 KiB u32)
#define NSLAB 256            // histogram slabs per graph
#define BORUVKA_ROUNDS 12

typedef __attribute__((ext_vector_type(8))) short short8;
typedef __attribute__((ext_vector_type(4))) float floatx4;
typedef __attribute__((ext_vector_type(4))) unsigned short ushort4_t;
typedef __attribute__((ext_vector_type(4))) int int4_t;

// ---------- helpers ----------
__device__ __forceinline__ unsigned bin_of(float v, float scale) {
  if (v < 0.f) v = 0.f;
  unsigned b = (unsigned)(v * scale);
  return b >= (unsigned)NBINS ? (unsigned)(NBINS - 1) : b;
}

// ---------- row squared norms for both graphs (fp32, matches reference) ----------
__global__ void k_rownorm(const float* __restrict__ x1, const float* __restrict__ x2,
                          float* __restrict__ sq) {
  int i = blockIdx.x * blockDim.x + threadIdx.x;
  if (i >= 2 * NN) return;
  const float* x = (i < NN) ? x1 : x2;
  int r = i & (NN - 1);
  const float* row = x + (size_t)r * DF;
  float s = 0.f;
  for (int k = 0; k < DF; ++k) s += row[k] * row[k];
  sq[i] = s;
}

// ---------- distance upper bound -> u16 quantization scales ----------
// hdrf: [0..1]=caps(u32), [2]=qscale, [3]=qinv
__global__ __launch_bounds__(256) void k_bound(const float* __restrict__ sq,
                                               float* __restrict__ hdrf) {
  int t = threadIdx.x;
  float m = 0.f;
  for (int i = t; i < 2 * NN; i += 256) m = fmaxf(m, sq[i]);
  for (int off = 32; off > 0; off >>= 1) m = fmaxf(m, __shfl_down(m, off, 64));
  __shared__ float wm[4];
  if ((t & 63) == 0) wm[t >> 6] = m;
  __syncthreads();
  if (t == 0) {
    float mm = fmaxf(fmaxf(wm[0], wm[1]), fmaxf(wm[2], wm[3]));
    float dbound = 2.f * sqrtf(mm);       // d <= |xi|+|xj| <= 2*max|x|
    hdrf[2] = 65535.f / dbound;
    hdrf[3] = dbound / 65535.f;
  }
}

// ---------- split fp32 -> (hi, lo) bf16 for error-compensated MFMA ----------
__global__ void k_split(const float* __restrict__ x1, const float* __restrict__ x2,
                        unsigned short* __restrict__ xh, unsigned short* __restrict__ xl) {
  int i = blockIdx.x * blockDim.x + threadIdx.x;
  if (i >= 2 * NN * DF) return;
  const float* x = (i < NN * DF) ? x1 : x2;
  float v = x[i & (NN * DF - 1)];
  unsigned u = __float_as_uint(v);
  unsigned hu = u & 0xffff0000u;
  float hf = __uint_as_float(hu);
  float lf = v - hf;
  unsigned lu = __float_as_uint(lf) & 0xffff0000u;
  xh[i] = (unsigned short)(hu >> 16);
  xl[i] = (unsigned short)(lu >> 16);
}

// ---------- distances via split-bf16 MFMA Gram, LDS-free, SYMMETRIC (R12-proven) ----------
__global__ __launch_bounds__(256) void k_dist(const unsigned short* __restrict__ Xhi,
                                              const unsigned short* __restrict__ Xlo,
                                              const float* __restrict__ sq,
                                              const float* __restrict__ hdrf,
                                              unsigned short* __restrict__ Qbase,
                                              unsigned* __restrict__ caps) {
  int bi = blockIdx.y, bj = blockIdx.x;
  if (bi > bj) return;                       // triangle only
  bool offdiag = (bi != bj);
  int g = blockIdx.z;
  const unsigned short* xh = Xhi + (size_t)g * NN * DF;
  const unsigned short* xl = Xlo + (size_t)g * NN * DF;
  const float* sqg = sq + g * NN;
  unsigned short* Q = Qbase + (size_t)g * NN * NN;
  float qs = hdrf[2];
  int t = threadIdx.x;
  int w = t >> 6, lane = t & 63;
  int m = lane & 15, quad = lane >> 4;
  int i0 = bi * 128 + (w >> 1) * 64;
  int j0 = bj * 128 + (w & 1) * 64;
  floatx4 acc[4][4];
#pragma unroll
  for (int ti = 0; ti < 4; ++ti)
#pragma unroll
    for (int tj = 0; tj < 4; ++tj) acc[ti][tj] = (floatx4){0.f, 0.f, 0.f, 0.f};
#pragma unroll
  for (int kc = 0; kc < DF; kc += 32) {
    short8 ah[4], al[4], bh[4], bl[4];
#pragma unroll
    for (int ti = 0; ti < 4; ++ti) {
      size_t ra = (size_t)(i0 + ti * 16 + m) * DF + kc + quad * 8;
      size_t rb = (size_t)(j0 + ti * 16 + m) * DF + kc + quad * 8;
      ah[ti] = *(const short8*)&xh[ra];
      al[ti] = *(const short8*)&xl[ra];
      bh[ti] = *(const short8*)&xh[rb];
      bl[ti] = *(const short8*)&xl[rb];
    }
#pragma unroll
    for (int ti = 0; ti < 4; ++ti)
#pragma unroll
      for (int tj = 0; tj < 4; ++tj) {
        acc[ti][tj] = __builtin_amdgcn_mfma_f32_16x16x32_bf16(ah[ti], bh[tj], acc[ti][tj], 0, 0, 0);
        acc[ti][tj] = __builtin_amdgcn_mfma_f32_16x16x32_bf16(ah[ti], bl[tj], acc[ti][tj], 0, 0, 0);
        acc[ti][tj] = __builtin_amdgcn_mfma_f32_16x16x32_bf16(al[ti], bh[tj], acc[ti][tj], 0, 0, 0);
      }
  }
  // C/D layout: col = lane&15 (j), row = quad*4 + reg (i)
  float sqj[4];
#pragma unroll
  for (int tj = 0; tj < 4; ++tj) sqj[tj] = sqg[j0 + tj * 16 + m];
  float mx = 0.f;
#pragma unroll
  for (int ti = 0; ti < 4; ++ti) {
    int ib = i0 + ti * 16 + quad * 4;
    float sqiv[4];
#pragma unroll
    for (int r = 0; r < 4; ++r) sqiv[r] = sqg[ib + r];
#pragma unroll
    for (int tj = 0; tj < 4; ++tj) {
      int jj = j0 + tj * 16 + m;
      ushort4_t qv;
#pragma unroll
      for (int r = 0; r < 4; ++r) {
        float d2 = sqiv[r] + sqj[tj] - 2.f * acc[ti][tj][r];
        d2 = fmaxf(d2, 0.f);
        float d = (d2 > 1e-12f) ? sqrtf(d2) : 0.f;
        mx = fmaxf(mx, d);
        unsigned q = (unsigned)(d * qs + 0.5f);
        if (q > 65535u) q = 65535u;
        qv[r] = (unsigned short)q;
      }
      // transposed half: one 8B store (4 consecutive i in row jj)
      *(ushort4_t*)&Q[(size_t)jj * NN + ib] = qv;
      // normal half (off-diagonal tiles only): scattered 2B stores
      if (offdiag) {
#pragma unroll
        for (int r = 0; r < 4; ++r) Q[(size_t)(ib + r) * NN + jj] = qv[r];
      }
    }
  }
  for (int off = 32; off > 0; off >>= 1) mx = fmaxf(mx, __shfl_down(mx, off, 64));
  __shared__ float wmax[4];
  if (lane == 0) wmax[w] = mx;
  __syncthreads();
  if (t == 0) {
    float mm = fmaxf(fmaxf(wmax[0], wmax[1]), fmaxf(wmax[2], wmax[3]));
    atomicMax(&caps[g], __float_as_uint(mm));
  }
}

// ---------- Boruvka init ----------
__global__ void k_binit(int* __restrict__ comp, unsigned long long* __restrict__ compbest,
                        unsigned long long* __restrict__ bestkey,
                        int* __restrict__ mstcnt, int* __restrict__ ncomp) {
  int i = blockIdx.x * blockDim.x + threadIdx.x;
  if (i >= 2 * NN) return;
  comp[i] = i & (NN - 1);
  compbest[i] = ~0ull;
  bestkey[i] = ~0ull;
  if ((i & (NN - 1)) == 0) {
    mstcnt[i >> 12] = 0;
    ncomp[i >> 12] = NN;
  }
}

// ---------- Boruvka step 1: WAVE-per-row min edge (no LDS, no block barrier) ----------
// key = (w16 << 24) | (v << 12) | j : unique => hook graph has only 2-cycles.
// Cached candidate valid while its target stays outside comp[v].
// 4 waves/block, wave w handles row blockIdx.x*4+w; grid 1/4 of one-block-per-row.
__global__ __launch_bounds__(256) void k_minedge(const unsigned short* __restrict__ Qbase,
                                                 const int* __restrict__ comp_base,
                                                 unsigned long long* __restrict__ compbest_base,
                                                 unsigned long long* __restrict__ bestkey_base,
                                                 const int* __restrict__ ncomp) {
  int g = blockIdx.y;
  if (ncomp[g] == 1) return;
  int w = threadIdx.x >> 6, lane = threadIdx.x & 63;
  int v = blockIdx.x * 4 + w;
  const int* comp = comp_base + g * NN;
  unsigned long long* cbest = compbest_base + (size_t)g * NN;
  unsigned long long* bkp = bestkey_base + (size_t)g * NN;
  int cv = comp[v];
  unsigned long long bk = bkp[v];
  if (bk != ~0ull) {
    int bj = (int)(bk & 0xfffull);
    if (comp[bj] != cv) {           // cache still valid: skip the row scan
      if (lane == 0) atomicMin(&cbest[cv], bk);
      return;
    }
  }
  const unsigned short* row = Qbase + ((size_t)g * NN + (size_t)v) * NN;
  unsigned long long best = ~0ull;
#pragma unroll 4
  for (int it = 0; it < NN / 256; ++it) {
    int jb = (it * 64 + lane) * 4;
    ushort4_t rw = *(const ushort4_t*)&row[jb];
    int4_t cj = *(const int4_t*)&comp[jb];
#pragma unroll
    for (int u = 0; u < 4; ++u) {
      if (cj[u] != cv) {
        unsigned long long key = ((unsigned long long)rw[u] << 24) |
                                 ((unsigned long long)v << 12) | (unsigned)(jb + u);
        if (key < best) best = key;
      }
    }
  }
  for (int off = 32; off > 0; off >>= 1) {
    unsigned long long o = __shfl_down(best, off, 64);
    if (o < best) best = o;
  }
  if (lane == 0) {
    bkp[v] = best;
    if (best != ~0ull) atomicMin(&cbest[cv], best);
  }
}

// ---------- Boruvka step 2: hook/contract (512 thr, early-exit jumping) ----------
__global__ __launch_bounds__(512) void k_hook(unsigned long long* __restrict__ compbest_base,
                                              int* __restrict__ comp_base,
                                              const float* __restrict__ hdrf,
                                              float* __restrict__ mstw_base,
                                              int* __restrict__ mstcnt,
                                              int* __restrict__ ncomp) {
  int g = blockIdx.x;
  if (ncomp[g] == 1) return;
  unsigned long long* cb = compbest_base + (size_t)g * NN;
  int* comp = comp_base + g * NN;
  float* mstw = mstw_base + g * (NN - 1);
  float qinv = hdrf[3];
  __shared__ int par[NN];
  __shared__ unsigned char live[NN];
  __shared__ int newcnt;
  int t = threadIdx.x;
  if (t == 0) newcnt = 0;
  for (int c = t; c < NN; c += 512) {
    unsigned long long key = cb[c];
    bool a = (key != ~0ull);
    live[c] = a ? 1 : 0;
    int p = c;
    if (a) {
      int j = (int)(key & 0xfffull);
      p = comp[j];
    }
    par[c] = p;
  }
  __syncthreads();
  // break 2-cycles: smaller label becomes root (each thread writes own slots)
  for (int c = t; c < NN; c += 512) {
    int p = par[c];
    if (p != c && par[p] == c && c < p) par[c] = c;
  }
  __syncthreads();
  // emit one MST weight per hooked component (dequantized)
  for (int c = t; c < NN; c += 512) {
    if (live[c] && par[c] != c) {
      float w = (float)((unsigned)(cb[c] >> 24)) * qinv;
      int slot = atomicAdd(&mstcnt[g], 1);
      mstw[slot] = w;
    }
  }
  __syncthreads();
  // pointer jumping until stable (hook forests are shallow: typ 2-4 iters)
  for (;;) {
    int np[NN / 512];
    bool ch = false;
    int k = 0;
    for (int c = t; c < NN; c += 512, ++k) {
      int p = par[c];
      int pp = par[p];
      np[k] = pp;
      if (pp != p) ch = true;
    }
    __syncthreads();
    k = 0;
    for (int c = t; c < NN; c += 512, ++k) par[c] = np[k];
    if (!__syncthreads_or(ch)) break;
  }
  // count roots
  int cnt = 0;
  for (int c = t; c < NN; c += 512)
    if (live[c] && par[c] == c) cnt++;
  for (int off = 32; off > 0; off >>= 1) cnt += __shfl_down(cnt, off, 64);
  if ((t & 63) == 0 && cnt) atomicAdd(&newcnt, cnt);
  // relabel vertices + reset compbest
  for (int v = t; v < NN; v += 512) comp[v] = par[comp[v]];
  for (int c = t; c < NN; c += 512) cb[c] = ~0ull;
  __syncthreads();
  if (t == 0) ncomp[g] = newcnt;
}

// ---------- histogram: per-block LDS hist over upper triangle (u16 D), slab dump ----------
__global__ __launch_bounds__(256) void k_hist(const unsigned short* __restrict__ Qbase,
                                              const unsigned* __restrict__ caps,
                                              const float* __restrict__ hdrf,
                                              unsigned* __restrict__ Hs) {
  __shared__ unsigned h[NBINS];
  int t = threadIdx.x;
  for (int i = t; i < NBINS; i += 256) h[i] = 0;
  int b = blockIdx.x;
  int g = b >> 8, s = b & (NSLAB - 1);
  const unsigned short* Q = Qbase + (size_t)g * NN * NN;
  float cap = __uint_as_float(caps[g]);
  float capmax = fmaxf(__uint_as_float(caps[0]), __uint_as_float(caps[1]));
  float scale = (float)NBINS / capmax;
  float qinv = hdrf[3];
  __syncthreads();
  for (int p = s; p < NN / 2; p += NSLAB) {
    int r1 = p, r2 = NN - 1 - p;
    const unsigned short* row1 = Q + (size_t)r1 * NN;
    const unsigned short* row2 = Q + (size_t)r2 * NN;
    for (int j = r1 + 1 + t; j < NN; j += 256)
      atomicAdd(&h[bin_of(cap - (float)row1[j] * qinv, scale)], 1u);
    for (int j = r2 + 1 + t; j < NN; j += 256)
      atomicAdd(&h[bin_of(cap - (float)row2[j] * qinv, scale)], 1u);
  }
  __syncthreads();
  unsigned* slab = Hs + (size_t)b * NBINS;
  for (int i = t; i < NBINS; i += 256) slab[i] = h[i];
}

// ---------- move tree edges to persistence 0 (slab 0; same dequant grid => exact) ----------
__global__ void k_treefix(const float* __restrict__ twbase, const unsigned* __restrict__ caps,
                          unsigned* __restrict__ Hs) {
  int g = blockIdx.y;
  unsigned* hist = Hs + (size_t)(g * NSLAB) * NBINS;
  float cap = __uint_as_float(caps[g]);
  float capmax = fmaxf(__uint_as_float(caps[0]), __uint_as_float(caps[1]));
  float scale = (float)NBINS / capmax;
  int idx = blockIdx.x * blockDim.x + threadIdx.x;
  if (idx < NN - 1) {
    float w = twbase[g * (NN - 1) + idx];
    atomicSub(&hist[bin_of(cap - w, scale)], 1u);  // may wrap; per-bin total stays >= 0
    atomicAdd(&hist[0], 1u);
  }
}

// ---------- merge 256 slabs per graph -> Hm[2][NBINS] ----------
__global__ __launch_bounds__(256) void k_merge(const unsigned* __restrict__ Hs,
                                               unsigned* __restrict__ Hm) {
  int id = blockIdx.x * 256 + threadIdx.x;  // 0 .. 2*NBINS-1
  int g = id >> 14;
  int i = id & (NBINS - 1);
  const unsigned* base = Hs + (size_t)(g * NSLAB) * NBINS + i;
  unsigned sum = 0;
  for (int s = 0; s < NSLAB; ++s) sum += base[(size_t)s * NBINS];
  Hm[id] = sum;
}

// ---------- W1: single block computes sum |running prefix| * dt ----------
__global__ __launch_bounds__(256) void k_w1(const unsigned* __restrict__ Hm,
                                            const unsigned* __restrict__ caps,
                                            float* __restrict__ out) {
  int t = threadIdx.x;
  const int PB = NBINS / 256;  // 64 bins per thread
  int base = t * PB;
  long long tsum = 0;
  for (int i = 0; i < PB; ++i)
    tsum += (long long)(int)(Hm[base + i] - Hm[NBINS + base + i]);
  int lane = t & 63, wid = t >> 6;
  long long incl = tsum;
  for (int off = 1; off < 64; off <<= 1) {
    long long o = __shfl_up(incl, off, 64);
    if (lane >= off) incl += o;
  }
  __shared__ long long wtot[4];
  if (lane == 63) wtot[wid] = incl;
  __syncthreads();
  long long run = incl - tsum;
  for (int w = 0; w < wid; ++w) run += wtot[w];
  unsigned long long local = 0;
  for (int i = 0; i < PB; ++i) {
    run += (long long)(int)(Hm[base + i] - Hm[NBINS + base + i]);
    local += (unsigned long long)(run < 0 ? -run : run);
  }
  for (int off = 32; off > 0; off >>= 1) local += __shfl_down(local, off, 64);
  __shared__ unsigned long long wl[4];
  if (lane == 0) wl[wid] = local;
  __syncthreads();
  if (t == 0) {
    float capmax = fmaxf(__uint_as_float(caps[0]), __uint_as_float(caps[1]));
    double dt = (double)capmax / (double)NBINS;
    out[0] = (float)((double)(wl[0] + wl[1] + wl[2] + wl[3]) * dt);
  }
}

__global__ void k_fail(float* out) { out[0] = -1234567.0f; }

extern "C" void kernel_launch(void* const* d_in, const int* in_sizes, int n_in,
                              void* d_out, int out_size, void* d_ws, size_t ws_size,
                              hipStream_t stream) {
  const float* x1 = (const float*)d_in[0];
  const float* x2 = (const float*)d_in[2];
  float* out = (float*)d_out;
  char* ws = (char*)d_ws;

  const size_t offQ = 0;                                        // u16 D: 64 MiB
  const size_t offS = 2ull * NN * NN * 2ull;                    // slabs: 32 MiB
  const size_t offHm = offS + 2ull * NSLAB * NBINS * 4ull;      // 128 KiB merged hist
  const size_t offHdr = offHm + 2ull * NBINS * 4ull;            // caps+qscale+qinv
  const size_t offSq = offHdr + 64;
  const size_t offTw = offSq + 2ull * NN * 4ull;
  const size_t offCb = (offTw + 2ull * (NN - 1) * 4ull + 7ull) & ~7ull;
  const size_t offBk = offCb + 2ull * NN * 8ull;                // bestkey cache
  const size_t offCp = offBk + 2ull * NN * 8ull;
  const size_t offMeta = offCp + 2ull * NN * 4ull;              // mstcnt[2], ncomp[2]
  const size_t needed = offMeta + 64;
  if (ws_size < needed) {
    hipLaunchKernelGGL(k_fail, dim3(1), dim3(1), 0, stream, out);
    return;
  }

  unsigned short* Qbase = (unsigned short*)(ws + offQ);
  unsigned* Hs = (unsigned*)(ws + offS);
  // Xhi/Xlo (4 MiB) transiently live in the slab region (dead before k_hist writes it)
  unsigned short* Xhi = (unsigned short*)(ws + offS);
  unsigned short* Xlo = (unsigned short*)(ws + offS + 2ull * NN * DF * 2ull);
  unsigned* Hm = (unsigned*)(ws + offHm);
  unsigned* caps = (unsigned*)(ws + offHdr);
  float* hdrf = (float*)(ws + offHdr);
  float* sq = (float*)(ws + offSq);
  float* tw = (float*)(ws + offTw);
  unsigned long long* compbest = (unsigned long long*)(ws + offCb);
  unsigned long long* bestkey = (unsigned long long*)(ws + offBk);
  int* comp = (int*)(ws + offCp);
  int* mstcnt = (int*)(ws + offMeta);
  int* ncomp = (int*)(ws + offMeta + 8);

  // zero header (caps; qscale/qinv overwritten by k_bound)
  hipMemsetAsync(ws + offHdr, 0, 64, stream);

  hipLaunchKernelGGL(k_rownorm, dim3((2 * NN + 255) / 256), dim3(256), 0, stream, x1, x2, sq);
  hipLaunchKernelGGL(k_bound, dim3(1), dim3(256), 0, stream, sq, hdrf);
  hipLaunchKernelGGL(k_split, dim3((2 * NN * DF + 255) / 256), dim3(256), 0, stream,
                     x1, x2, Xhi, Xlo);
  hipLaunchKernelGGL(k_dist, dim3(NN / 128, NN / 128, 2), dim3(256), 0, stream,
                     Xhi, Xlo, sq, hdrf, Qbase, caps);
  hipLaunchKernelGGL(k_binit, dim3((2 * NN + 255) / 256), dim3(256), 0, stream,
                     comp, compbest, bestkey, mstcnt, ncomp);
  for (int r = 0; r < BORUVKA_ROUNDS; ++r) {
    hipLaunchKernelGGL(k_minedge, dim3(NN / 4, 2), dim3(256), 0, stream,
                       Qbase, comp, compbest, bestkey, ncomp);
    hipLaunchKernelGGL(k_hook, dim3(2), dim3(512), 0, stream,
                       compbest, comp, hdrf, tw, mstcnt, ncomp);
  }
  hipLaunchKernelGGL(k_hist, dim3(2 * NSLAB), dim3(256), 0, stream, Qbase, caps, hdrf, Hs);
  hipLaunchKernelGGL(k_treefix, dim3(16, 2), dim3(256), 0, stream, tw, caps, Hs);
  hipLaunchKernelGGL(k_merge, dim3(2 * NBINS / 256), dim3(256), 0, stream, Hs, Hm);
  hipLaunchKernelGGL(k_w1, dim3(1), dim3(256), 0, stream, Hm, caps, out);
}